// Round 14
// baseline (866.463 us; speedup 1.0000x reference)
//
#include <hip/hip_runtime.h>
#include <math.h>

namespace {

constexpr int B_ = 4, L_ = 1024, H_ = 1024, NH_ = 16, HD_ = 64, ND_ = 1024, ITERS_ = 4;

typedef unsigned short u16;
typedef __attribute__((ext_vector_type(8))) short short8;
typedef __attribute__((ext_vector_type(4))) float f32x4;

__device__ inline u16 f2bf(float f) {
  unsigned u = __builtin_bit_cast(unsigned, f);
  u += 0x7FFFu + ((u >> 16) & 1u);
  return (u16)(u >> 16);
}
__device__ inline float bf2f(u16 v) {
  unsigned u = ((unsigned)v) << 16;
  return __builtin_bit_cast(float, u);
}

__device__ inline void gl_lds16(const u16* g, u16* l) {
  __builtin_amdgcn_global_load_lds((const __attribute__((address_space(1))) void*)g,
                                   (__attribute__((address_space(3))) void*)l, 16, 0, 0);
}

// ---------- prep: 6 f2bf conversions + nodes copy ----------
__global__ void k_prep(const float* __restrict__ data, const float* __restrict__ rwq,
                       const float* __restrict__ rwk, const float* __restrict__ rwv,
                       const float* __restrict__ rwo, const float* __restrict__ swk,
                       u16* __restrict__ embs_bf, u16* __restrict__ wq_bf,
                       u16* __restrict__ wk_bf, u16* __restrict__ wv_bf,
                       u16* __restrict__ wo_bf, u16* __restrict__ swk_bf,
                       float* __restrict__ nodes) {
  int i = blockIdx.x * 256 + threadIdx.x;
  int which = blockIdx.y;
  if (which == 6) {
    reinterpret_cast<float4*>(nodes)[i] = reinterpret_cast<const float4*>(data)[i];
    return;
  }
  const float* src;
  u16* dst;
  switch (which) {
    case 0: src = data; dst = embs_bf; break;
    case 1: src = rwq; dst = wq_bf; break;
    case 2: src = rwk; dst = wk_bf; break;
    case 3: src = rwv; dst = wv_bf; break;
    case 4: src = rwo; dst = wo_bf; break;
    default: src = swk; dst = swk_bf; break;
  }
  float4 v = reinterpret_cast<const float4*>(src)[i];
  ushort4 o;
  o.x = f2bf(v.x); o.y = f2bf(v.y); o.z = f2bf(v.z); o.w = f2bf(v.w);
  reinterpret_cast<ushort4*>(dst)[i] = o;
}

// ---------- relay init ----------
__global__ void k_relay_part(const float* __restrict__ data, float* __restrict__ part) {
  int b = blockIdx.z, chunk = blockIdx.y;
  int c = blockIdx.x * 256 + threadIdx.x;
  const float* p = data + ((size_t)b * L_ + chunk * 128) * H_ + c;
  float acc = 0.f;
  for (int l = 0; l < 128; ++l) acc += p[(size_t)l * H_];
  part[((size_t)b * 8 + chunk) * H_ + c] = acc;
}
__global__ void k_relay_reduce(const float* __restrict__ part, float* __restrict__ relay) {
  int i = blockIdx.x * 256 + threadIdx.x;
  int b = i >> 10, c = i & 1023;
  float acc = 0.f;
  for (int j = 0; j < 8; ++j) acc += part[((size_t)b * 8 + j) * H_ + c];
  relay[i] = acc * (1.f / (float)L_);
}

// ---------- LayerNorm rows of nodes [B,L,H]; fused pad-row zeroing ----------
__global__ __launch_bounds__(256) void k_layernorm_bf(float* __restrict__ nodes,
                                                      const float* __restrict__ s,
                                                      const float* __restrict__ bb,
                                                      const int* __restrict__ mask,
                                                      u16* __restrict__ y, int do_zero) {
  int row = blockIdx.x * 4 + (threadIdx.x >> 6);
  int lane = threadIdx.x & 63;
  int b = row >> 10, l = row & 1023;
  bool pad = do_zero && (mask[b * L_ + l] == 0);
  float4* xr = reinterpret_cast<float4*>(nodes + (size_t)row * H_);
  float4 v[4];
  float sum = 0.f, sq = 0.f;
#pragma unroll
  for (int j = 0; j < 4; ++j) {
    v[j] = pad ? float4{0.f, 0.f, 0.f, 0.f} : xr[lane + 64 * j];
    sum += v[j].x + v[j].y + v[j].z + v[j].w;
    sq += v[j].x * v[j].x + v[j].y * v[j].y + v[j].z * v[j].z + v[j].w * v[j].w;
  }
  if (pad) {
#pragma unroll
    for (int j = 0; j < 4; ++j) xr[lane + 64 * j] = float4{0.f, 0.f, 0.f, 0.f};
  }
#pragma unroll
  for (int off = 32; off; off >>= 1) {
    sum += __shfl_xor(sum, off);
    sq += __shfl_xor(sq, off);
  }
  float mu = sum * (1.f / (float)H_);
  float rstd = rsqrtf(sq * (1.f / (float)H_) - mu * mu + 1e-5f);
  ushort4* yr = reinterpret_cast<ushort4*>(y + (size_t)row * H_);
#pragma unroll
  for (int j = 0; j < 4; ++j) {
    int c4 = lane + 64 * j;
    float4 sc = reinterpret_cast<const float4*>(s)[c4];
    float4 bc = reinterpret_cast<const float4*>(bb)[c4];
    ushort4 o;
    o.x = f2bf((v[j].x - mu) * rstd * sc.x + bc.x);
    o.y = f2bf((v[j].y - mu) * rstd * sc.y + bc.y);
    o.z = f2bf((v[j].z - mu) * rstd * sc.z + bc.z);
    o.w = f2bf((v[j].w - mu) * rstd * sc.w + bc.w);
    yr[c4] = o;
  }
}

// ================= 128x128 GEMM, BK=64: X via LDS, W direct global->VGPR =================
// LDS traffic halved (X only, 16KB); W fragments are 16-row x 64B coalesced loads
// hitting L2 (panel 256KB, block-reused) and L1 (shared across bl-wave-groups).

// ---- 5-in-1 GEMM, swapped orientation (A=W -> M=o, B=X -> N=l(B*L)) ----
__global__ __launch_bounds__(256, 3) void k_gemm5(const u16* __restrict__ wq,
                                                  const u16* __restrict__ wk,
                                                  const u16* __restrict__ wv,
                                                  const float* __restrict__ bq,
                                                  const float* __restrict__ bk,
                                                  const float* __restrict__ bv,
                                                  const u16* __restrict__ xn,
                                                  const u16* __restrict__ embs,
                                                  u16* __restrict__ Y) {
  __shared__ __align__(16) u16 sX[2][128 * 32];
  const int bm = blockIdx.x * 128;            // bl rows
  const int which = blockIdx.y >> 3;
  const int bn = (blockIdx.y & 7) * 128;      // o
  const u16* W = (which == 0) ? wq : ((which == 1 || which == 3) ? wk : wv);
  const float* bias = (which == 0) ? bq : ((which == 1 || which == 3) ? bk : bv);
  const u16* X = (which < 3) ? xn : embs;
  u16* Yw = Y + (size_t)which * ((size_t)B_ * L_ * ND_);

  const int t = threadIdx.x;
  const int w = t >> 6, lane = t & 63;
  const int wm = w >> 1, wn = w & 1;
  const int r4 = lane >> 2, slot = lane & 3;
  const int rowS0 = w * 16 + r4, rowS1 = 64 + rowS0;
  const int colS0 = ((slot ^ ((rowS0 >> 1) & 3)) << 3);
  const int colS1 = ((slot ^ ((rowS1 >> 1) & 3)) << 3);
  const u16* gX0 = X + (size_t)(bm + rowS0) * 1024 + colS0;
  const u16* gX1 = X + (size_t)(bm + rowS1) * 1024 + colS1;
  const int kidx = (((lane >> 4) ^ ((lane >> 1) & 3)) << 3);
  const int rX = wn * 64 + (lane & 15);
  // W direct pointers: row = bn + wm*64 + mf*16 + (lane&15), kcol = (lane>>4)*8
  const u16* gWf[4];
#pragma unroll
  for (int mf = 0; mf < 4; ++mf)
    gWf[mf] = W + (size_t)(bn + wm * 64 + mf * 16 + (lane & 15)) * 1024 + ((lane >> 4) << 3);

  f32x4 acc[4][4];
#pragma unroll
  for (int i_ = 0; i_ < 4; ++i_)
#pragma unroll
    for (int j_ = 0; j_ < 4; ++j_) acc[i_][j_] = f32x4{0.f, 0.f, 0.f, 0.f};

  for (int ck = 0; ck < 1024; ck += 64) {
    gl_lds16(gX0, sX[0] + w * 512);
    gl_lds16(gX0 + 32, sX[1] + w * 512);
    gl_lds16(gX1, sX[0] + (4 + w) * 512);
    gl_lds16(gX1 + 32, sX[1] + (4 + w) * 512);
    gX0 += 64; gX1 += 64;
    short8 wf[2][4];
#pragma unroll
    for (int h = 0; h < 2; ++h)
#pragma unroll
      for (int mf = 0; mf < 4; ++mf)
        wf[h][mf] = *reinterpret_cast<const short8*>(gWf[mf] + h * 32);
#pragma unroll
    for (int mf = 0; mf < 4; ++mf) gWf[mf] += 64;
    __syncthreads();
#pragma unroll
    for (int h = 0; h < 2; ++h) {
      short8 bx[4];
#pragma unroll
      for (int nf = 0; nf < 4; ++nf)
        bx[nf] = *reinterpret_cast<const short8*>(&sX[h][(rX + nf * 16) * 32 + kidx]);
#pragma unroll
      for (int mf = 0; mf < 4; ++mf)
#pragma unroll
        for (int nf = 0; nf < 4; ++nf)
          acc[mf][nf] = __builtin_amdgcn_mfma_f32_16x16x32_bf16(wf[h][mf], bx[nf], acc[mf][nf], 0, 0, 0);
    }
    __syncthreads();
  }

#pragma unroll
  for (int mo = 0; mo < 4; ++mo) {
    int o0 = bn + wm * 64 + mo * 16 + ((lane >> 4) << 2);
    float4 bs = *reinterpret_cast<const float4*>(bias + o0);
#pragma unroll
    for (int nl = 0; nl < 4; ++nl) {
      int bl = bm + wn * 64 + nl * 16 + (lane & 15);
      f32x4 vv = acc[mo][nl];
      ushort4 ov;
      ov.x = f2bf(vv[0] + bs.x);
      ov.y = f2bf(vv[1] + bs.y);
      ov.z = f2bf(vv[2] + bs.z);
      ov.w = f2bf(vv[3] + bs.w);
      *reinterpret_cast<ushort4*>(&Yw[(size_t)bl * 1024 + o0]) = ov;
    }
  }
}

// ================= 64(o) x 128(bl) bodies (wo / kkb_sw): X via LDS, W direct =================

#define SMALL_PROLOGUE(XPTR, WPTR)                                             \
  __shared__ __align__(16) u16 sX[2][128 * 32];                                \
  const int t = threadIdx.x;                                                   \
  const int w = t >> 6, lane = t & 63;                                         \
  const int wm = w >> 1, wn = w & 1;                                           \
  const int r4 = lane >> 2, slot = lane & 3;                                   \
  const int rowS0 = w * 16 + r4, rowS1 = 64 + rowS0;                           \
  const int colS0 = ((slot ^ ((rowS0 >> 1) & 3)) << 3);                        \
  const int colS1 = ((slot ^ ((rowS1 >> 1) & 3)) << 3);                        \
  const u16* gX0 = (XPTR) + (size_t)(bm + rowS0) * 1024 + colS0;               \
  const u16* gX1 = (XPTR) + (size_t)(bm + rowS1) * 1024 + colS1;               \
  const int kidx = (((lane >> 4) ^ ((lane >> 1) & 3)) << 3);                   \
  const int rX = wn * 64 + (lane & 15);                                        \
  const u16* gWf[2];                                                           \
  _Pragma("unroll") for (int mf = 0; mf < 2; ++mf)                             \
      gWf[mf] = (WPTR) + (size_t)(bn + wm * 32 + mf * 16 + (lane & 15)) * 1024 \
                + ((lane >> 4) << 3);                                          \
  f32x4 acc[2][4];                                                             \
  _Pragma("unroll") for (int i_ = 0; i_ < 2; ++i_)                             \
      _Pragma("unroll") for (int j_ = 0; j_ < 4; ++j_)                         \
          acc[i_][j_] = f32x4{0.f, 0.f, 0.f, 0.f};

#define SMALL_KLOOP()                                                          \
  for (int ck = 0; ck < 1024; ck += 64) {                                      \
    gl_lds16(gX0, sX[0] + w * 512);                                            \
    gl_lds16(gX0 + 32, sX[1] + w * 512);                                       \
    gl_lds16(gX1, sX[0] + (4 + w) * 512);                                      \
    gl_lds16(gX1 + 32, sX[1] + (4 + w) * 512);                                 \
    gX0 += 64; gX1 += 64;                                                      \
    short8 wf[2][2];                                                           \
    _Pragma("unroll") for (int h = 0; h < 2; ++h)                              \
        _Pragma("unroll") for (int mf = 0; mf < 2; ++mf)                       \
            wf[h][mf] = *reinterpret_cast<const short8*>(gWf[mf] + h * 32);    \
    _Pragma("unroll") for (int mf = 0; mf < 2; ++mf) gWf[mf] += 64;            \
    __syncthreads();                                                           \
    _Pragma("unroll") for (int h = 0; h < 2; ++h) {                            \
      short8 bx[4];                                                            \
      _Pragma("unroll") for (int nf = 0; nf < 4; ++nf)                         \
          bx[nf] = *reinterpret_cast<const short8*>(                           \
              &sX[h][(rX + nf * 16) * 32 + kidx]);                             \
      _Pragma("unroll") for (int mf = 0; mf < 2; ++mf)                         \
          _Pragma("unroll") for (int nf = 0; nf < 4; ++nf)                     \
              acc[mf][nf] = __builtin_amdgcn_mfma_f32_16x16x32_bf16(           \
                  wf[h][mf], bx[nf], acc[mf][nf], 0, 0, 0);                    \
    }                                                                          \
    __syncthreads();                                                          \
  }

// ---- Wo GEMM (A=W M=o 64, B=X N=bl 128); grid (32, 16) ----
__global__ __launch_bounds__(256, 3) void k_gemm_wo_s(const u16* __restrict__ W,
                                                      const float* __restrict__ bias,
                                                      const u16* __restrict__ X,
                                                      float* __restrict__ nodes,
                                                      u16* __restrict__ nodes_bf) {
  const int bm = blockIdx.x * 128;  // bl
  const int bn = blockIdx.y * 64;   // o
  SMALL_PROLOGUE(X, W)
  SMALL_KLOOP()

#pragma unroll
  for (int mo = 0; mo < 2; ++mo) {
    int o0 = bn + wm * 32 + mo * 16 + ((lane >> 4) << 2);
    float4 bs = *reinterpret_cast<const float4*>(bias + o0);
#pragma unroll
    for (int nl = 0; nl < 4; ++nl) {
      int bl = bm + wn * 64 + nl * 16 + (lane & 15);
      size_t ni = (size_t)bl * 1024 + o0;
      float4 curv = *reinterpret_cast<const float4*>(&nodes[ni]);
      f32x4 vv = acc[mo][nl];
      float r0 = vv[0] + bs.x; r0 = curv.x + (r0 > 0.f ? r0 : 0.01f * r0);
      float r1 = vv[1] + bs.y; r1 = curv.y + (r1 > 0.f ? r1 : 0.01f * r1);
      float r2 = vv[2] + bs.z; r2 = curv.z + (r2 > 0.f ? r2 : 0.01f * r2);
      float r3 = vv[3] + bs.w; r3 = curv.w + (r3 > 0.f ? r3 : 0.01f * r3);
      *reinterpret_cast<float4*>(&nodes[ni]) = float4{r0, r1, r2, r3};
      ushort4 ov;
      ov.x = f2bf(r0); ov.y = f2bf(r1); ov.z = f2bf(r2); ov.w = f2bf(r3);
      *reinterpret_cast<ushort4*>(&nodes_bf[ni]) = ov;
    }
  }
}

// ---- kkb GEMM: out bf16 [b][1+l][o]; grid (32, 16) ----
__global__ __launch_bounds__(256, 3) void k_gemm_kkb_sw(const u16* __restrict__ W,
                                                        const float* __restrict__ bias,
                                                        const u16* __restrict__ X,
                                                        u16* __restrict__ Y) {
  const int bm = blockIdx.x * 128;  // bl
  const int bn = blockIdx.y * 64;   // o
  SMALL_PROLOGUE(X, W)
  SMALL_KLOOP()

#pragma unroll
  for (int mo = 0; mo < 2; ++mo) {
    int o0 = bn + wm * 32 + mo * 16 + ((lane >> 4) << 2);
    float4 bs = *reinterpret_cast<const float4*>(bias + o0);
#pragma unroll
    for (int nl = 0; nl < 4; ++nl) {
      int bl = bm + wn * 64 + nl * 16 + (lane & 15);
      size_t row = (size_t)(bl >> 10) * 1025 + 1 + (bl & 1023);
      f32x4 vv = acc[mo][nl];
      ushort4 ov;
      ov.x = f2bf(vv[0] + bs.x);
      ov.y = f2bf(vv[1] + bs.y);
      ov.z = f2bf(vv[2] + bs.z);
      ov.w = f2bf(vv[3] + bs.w);
      *reinterpret_cast<ushort4*>(&Y[row * 1024 + o0]) = ov;
    }
  }
}

// ---------- quad matvec: rk, rv, rq (fp32) and kkb_sw row 0 (bf16) ----------
__global__ __launch_bounds__(256) void k_matvec4(const float* __restrict__ W0,
                                                 const float* __restrict__ b0, float* __restrict__ y0,
                                                 const float* __restrict__ W1,
                                                 const float* __restrict__ b1, float* __restrict__ y1,
                                                 const float* __restrict__ W2,
                                                 const float* __restrict__ b2, float* __restrict__ y2,
                                                 const float* __restrict__ W3,
                                                 const float* __restrict__ b3, u16* __restrict__ y3b,
                                                 const float* __restrict__ x) {
  int b = blockIdx.y, z = blockIdx.z;
  const float* W = (z == 0) ? W0 : (z == 1) ? W1 : (z == 2) ? W2 : W3;
  const float* bias = (z == 0) ? b0 : (z == 1) ? b1 : (z == 2) ? b2 : b3;
  int o = blockIdx.x * 4 + (threadIdx.x >> 6);
  int lane = threadIdx.x & 63;
  const float* wr = W + (size_t)o * 1024;
  const float* xb = x + (size_t)b * 1024;
  float acc = 0.f;
  for (int c = lane; c < 1024; c += 64) acc += wr[c] * xb[c];
#pragma unroll
  for (int off = 32; off; off >>= 1) acc += __shfl_xor(acc, off);
  if (lane == 0) {
    acc += bias[o];
    if (z == 3) y3b[(size_t)b * 1025 * 1024 + o] = f2bf(acc);
    else if (z == 2) y2[(size_t)b * 1024 + o] = acc;
    else if (z == 1) y1[(size_t)b * 1024 + o] = acc;
    else y0[(size_t)b * 1024 + o] = acc;
  }
}

// ---------- single matvec ----------
__global__ __launch_bounds__(256) void k_matvec(const float* __restrict__ W,
                                                const float* __restrict__ bias,
                                                const float* __restrict__ x,
                                                float* __restrict__ y, int leaky) {
  int b = blockIdx.y;
  int o = blockIdx.x * 4 + (threadIdx.x >> 6);
  int lane = threadIdx.x & 63;
  const float* wr = W + (size_t)o * 1024;
  const float* xb = x + (size_t)b * 1024;
  float acc = 0.f;
  for (int c = lane; c < 1024; c += 64) acc += wr[c] * xb[c];
#pragma unroll
  for (int off = 32; off; off >>= 1) acc += __shfl_xor(acc, off);
  if (lane == 0) {
    acc += bias[o];
    if (leaky) acc = acc > 0.f ? acc : 0.01f * acc;
    y[(size_t)b * 1024 + o] = acc;
  }
}

// ---------- msa1 ring attention: 16 d per thread, 4 l per block ----------
__global__ __launch_bounds__(256) void k_msa1(const u16* __restrict__ q,
                                              const u16* __restrict__ k,
                                              const u16* __restrict__ v,
                                              const u16* __restrict__ ke,
                                              const u16* __restrict__ ve,
                                              const float* __restrict__ rk,
                                              const float* __restrict__ rv,
                                              u16* __restrict__ attbf) {
  int t = threadIdx.x;
  int wv = t >> 6, lane = t & 63;
  int head = lane >> 2, dq = lane & 3;
  int l = blockIdx.x * 4 + wv;
  int b = blockIdx.z;
  size_t row = ((size_t)(b * 1024 + l)) * 1024 + head * 64 + dq * 16;
  size_t rbase = (size_t)b * 1024 + head * 64 + dq * 16;

  float qf[16];
  {
    const short8* qp = reinterpret_cast<const short8*>(q + row);
#pragma unroll
    for (int j = 0; j < 2; ++j) {
      short8 qv = qp[j];
#pragma unroll
      for (int e = 0; e < 8; ++e) qf[j * 8 + e] = bf2f((u16)qv[e]);
    }
  }
  float s[7];
#pragma unroll
  for (int u = 0; u < 5; ++u) {
    int lk = l + u - 2;
    float su = 0.f;
    if (lk >= 0 && lk < L_) {
      const short8* kp = reinterpret_cast<const short8*>(
          k + ((size_t)(b * 1024 + lk)) * 1024 + head * 64 + dq * 16);
#pragma unroll
      for (int j = 0; j < 2; ++j) {
        short8 kv = kp[j];
#pragma unroll
        for (int e = 0; e < 8; ++e) su = fmaf(qf[j * 8 + e], bf2f((u16)kv[e]), su);
      }
    }
    s[u] = su;
  }
  {
    float su = 0.f;
    const short8* kp = reinterpret_cast<const short8*>(ke + row);
#pragma unroll
    for (int j = 0; j < 2; ++j) {
      short8 kv = kp[j];
#pragma unroll
      for (int e = 0; e < 8; ++e) su = fmaf(qf[j * 8 + e], bf2f((u16)kv[e]), su);
    }
    s[5] = su;
  }
  {
    float su = 0.f;
    const float4* rp = reinterpret_cast<const float4*>(rk + rbase);
#pragma unroll
    for (int j = 0; j < 4; ++j) {
      float4 r4 = rp[j];
      su = fmaf(qf[j * 4 + 0], r4.x, su);
      su = fmaf(qf[j * 4 + 1], r4.y, su);
      su = fmaf(qf[j * 4 + 2], r4.z, su);
      su = fmaf(qf[j * 4 + 3], r4.w, su);
    }
    s[6] = su;
  }
#pragma unroll
  for (int u = 0; u < 7; ++u) {
    s[u] += __shfl_xor(s[u], 1);
    s[u] += __shfl_xor(s[u], 2);
  }
  float m = -1e30f;
#pragma unroll
  for (int u = 0; u < 7; ++u) {
    s[u] *= 0.125f;
    m = fmaxf(m, s[u]);
  }
  float e[7], tot = 0.f;
#pragma unroll
  for (int u = 0; u < 7; ++u) {
    e[u] = expf(s[u] - m);
    tot += e[u];
  }
  float inv = 1.f / tot;
#pragma unroll
  for (int u = 0; u < 7; ++u) e[u] *= inv;

  float av[16];
  {
    const float4* rp = reinterpret_cast<const float4*>(rv + rbase);
#pragma unroll
    for (int j = 0; j < 4; ++j) {
      float4 r4 = rp[j];
      av[j * 4 + 0] = e[6] * r4.x;
      av[j * 4 + 1] = e[6] * r4.y;
      av[j * 4 + 2] = e[6] * r4.z;
      av[j * 4 + 3] = e[6] * r4.w;
    }
  }
  {
    const short8* vp = reinterpret_cast<const short8*>(ve + row);
#pragma unroll
    for (int j = 0; j < 2; ++j) {
      short8 vvv = vp[j];
#pragma unroll
      for (int ee = 0; ee < 8; ++ee) av[j * 8 + ee] = fmaf(e[5], bf2f((u16)vvv[ee]), av[j * 8 + ee]);
    }
  }
#pragma unroll
  for (int u = 0; u < 5; ++u) {
    int lk = l + u - 2;
    if (lk >= 0 && lk < L_) {
      const short8* vp = reinterpret_cast<const short8*>(
          v + ((size_t)(b * 1024 + lk)) * 1024 + head * 64 + dq * 16);
#pragma unroll
      for (int j = 0; j < 2; ++j) {
        short8 vvv = vp[j];
#pragma unroll
        for (int ee = 0; ee < 8; ++ee) av[j * 8 + ee] = fmaf(e[u], bf2f((u16)vvv[ee]), av[j * 8 + ee]);
      }
    }
  }
  u16 ob[16];
#pragma unroll
  for (int j = 0; j < 16; ++j) ob[j] = f2bf(av[j]);
  uint4* d4 = reinterpret_cast<uint4*>(attbf + row);
  const uint4* s4 = reinterpret_cast<const uint4*>(ob);
  d4[0] = s4[0];
  d4[1] = s4[1];
}

// ---------- msa2 flash-style: wave per 16-position chunk (v = k, faithful) ----------
__global__ __launch_bounds__(256) void k_msa2f(const u16* __restrict__ kkb,
                                               const float* __restrict__ rq,
                                               const int* __restrict__ mask,
                                               float* __restrict__ avp,
                                               float* __restrict__ Ep) {
  int b = blockIdx.y;
  int w = threadIdx.x >> 6, lane = threadIdx.x & 63;
  int wc = blockIdx.x * 4 + w;  // 0..67
  int q4 = lane & 3;
  int ch0 = lane * 16;
  float rqv[16];
  {
    const float4* rp = reinterpret_cast<const float4*>(rq + (size_t)b * 1024 + ch0);
#pragma unroll
    for (int j = 0; j < 4; ++j) {
      float4 v4 = rp[j];
      rqv[j * 4 + 0] = v4.x; rqv[j * 4 + 1] = v4.y;
      rqv[j * 4 + 2] = v4.z; rqv[j * 4 + 3] = v4.w;
    }
  }
  float av[16];
#pragma unroll
  for (int j = 0; j < 16; ++j) av[j] = 0.f;
  float eacc = 0.f;
  int p0 = wc * 16;
  int pend = p0 + 16;
  if (pend > 1025) pend = 1025;
  for (int p = p0; p < pend; ++p) {
    if (p > 0 && mask[b * L_ + p - 1] == 0) continue;  // wave-uniform
    const uint4* kr = reinterpret_cast<const uint4*>(kkb + ((size_t)b * 1025 + p) * 1024 + ch0);
    uint4 ka = kr[0], kb2 = kr[1];
    float kf[16];
    const u16* kp = reinterpret_cast<const u16*>(&ka);
#pragma unroll
    for (int j = 0; j < 8; ++j) kf[j] = bf2f(kp[j]);
    const u16* kp2 = reinterpret_cast<const u16*>(&kb2);
#pragma unroll
    for (int j = 0; j < 8; ++j) kf[8 + j] = bf2f(kp2[j]);
    float s = 0.f;
#pragma unroll
    for (int j = 0; j < 16; ++j) s = fmaf(rqv[j], kf[j], s);
    s += __shfl_xor(s, 1);
    s += __shfl_xor(s, 2);
    float e = expf(s * 0.125f);
    if (q4 == 0) eacc += e;
#pragma unroll
    for (int j = 0; j < 16; ++j) av[j] = fmaf(e, kf[j], av[j]);
  }
  float* ap = avp + ((size_t)b * 68 + wc) * 1024 + ch0;
#pragma unroll
  for (int j = 0; j < 4; ++j)
    reinterpret_cast<float4*>(ap)[j] =
        float4{av[j * 4 + 0], av[j * 4 + 1], av[j * 4 + 2], av[j * 4 + 3]};
  if (q4 == 0) Ep[((size_t)b * 68 + wc) * 16 + (lane >> 2)] = eacc;
}

// ---------- msa2 reduce: satt = (sum avp) / (sum Ep) ----------
__global__ void k_msa2r(const float* __restrict__ avp, const float* __restrict__ Ep,
                        float* __restrict__ satt) {
  int b = blockIdx.y;
  int idx = blockIdx.x * 256 + threadIdx.x;  // 0..1023
  int head = idx >> 6;
  float a = 0.f, E = 0.f;
  for (int k = 0; k < 68; ++k) a += avp[((size_t)b * 68 + k) * 1024 + idx];
  for (int k = 0; k < 68; ++k) E += Ep[((size_t)b * 68 + k) * 16 + head];
  satt[(size_t)b * 1024 + idx] = a / E;
}

// ---------- final: out = pad ? 0 : nodes ----------
__global__ void k_final(const float* __restrict__ nodes, const int* __restrict__ mask,
                        float* __restrict__ out) {
  int i = blockIdx.x * 256 + threadIdx.x;
  int row = i >> 8;
  int b = row >> 10, l = row & 1023;
  float4 v = (mask[b * L_ + l] == 0) ? float4{0.f, 0.f, 0.f, 0.f}
                                     : reinterpret_cast<const float4*>(nodes)[i];
  reinterpret_cast<float4*>(out)[i] = v;
}

__global__ void k_copy_relay(const float* __restrict__ relay, float* __restrict__ out) {
  int i = blockIdx.x * 256 + threadIdx.x;
  out[i] = relay[i];
}

}  // namespace

extern "C" void kernel_launch(void* const* d_in, const int* in_sizes, int n_in,
                              void* d_out, int out_size, void* d_ws, size_t ws_size,
                              hipStream_t stream) {
  (void)in_sizes; (void)n_in; (void)out_size; (void)ws_size;
  const float* data = (const float*)d_in[0];
  const int* mask = (const int*)d_in[1];
  const float* ln_s = (const float*)d_in[2];
  const float* ln_b = (const float*)d_in[3];
  const float* rwq = (const float*)d_in[4];
  const float* rwq_b = (const float*)d_in[5];
  const float* rwk = (const float*)d_in[6];
  const float* rwk_b = (const float*)d_in[7];
  const float* rwv = (const float*)d_in[8];
  const float* rwv_b = (const float*)d_in[9];
  const float* rwo = (const float*)d_in[10];
  const float* rwo_b = (const float*)d_in[11];
  const float* swq = (const float*)d_in[12];
  const float* swq_b = (const float*)d_in[13];
  const float* swk = (const float*)d_in[14];
  const float* swk_b = (const float*)d_in[15];
  const float* swo = (const float*)d_in[16];
  const float* swo_b = (const float*)d_in[17];
  float* out = (float*)d_out;

  const size_t SZ = (size_t)B_ * ND_ * L_;  // 4M elements
  float* f = (float*)d_ws;
  float* nodes = f; f += SZ;                       // fp32 [B,L,H]
  float* part = f; f += (size_t)B_ * 8 * H_;
  float* relay = f; f += B_ * H_;
  float* rk = f; f += B_ * ND_;
  float* rv = f; f += B_ * ND_;
  float* rq = f; f += B_ * ND_;
  float* satt = f; f += B_ * ND_;
  float* avp = f; f += (size_t)B_ * 68 * 1024;
  float* Ep = f; f += (size_t)B_ * 68 * 16;
  u16* u = (u16*)f;
  u16* xn_bf = u; u += SZ;       // [B,L,H]
  u16* embs_bf = u; u += SZ;     // [B,L,H]
  u16* att_bf = u; u += SZ;      // [B,L,ND]
  u16* nodes_bf = u; u += SZ;    // [B,L,H]
  u16* kkb_sw = u; u += (size_t)B_ * 1025 * 1024;  // bf16 [b][p][o]
  u16* qkv5_bf = u; u += 5 * SZ; // [5][B,L,ND]: q,k,v,ke,ve
  u16* wq_bf = u; u += SZ;
  u16* wk_bf = u; u += SZ;
  u16* wv_bf = u; u += SZ;
  u16* wo_bf = u; u += SZ;
  u16* swk_bf = u; u += SZ;

  k_prep<<<dim3(4096, 7), 256, 0, stream>>>(data, rwq, rwk, rwv, rwo, swk,
                                            embs_bf, wq_bf, wk_bf, wv_bf, wo_bf, swk_bf, nodes);
  k_relay_part<<<dim3(H_ / 256, 8, B_), 256, 0, stream>>>(data, part);
  k_relay_reduce<<<dim3((B_ * H_) / 256), 256, 0, stream>>>(part, relay);

  for (int i = 0; i < ITERS_; ++i) {
    const u16* wq_i = wq_bf + (size_t)i * ND_ * H_;
    const u16* wk_i = wk_bf + (size_t)i * ND_ * H_;
    const u16* wv_i = wv_bf + (size_t)i * ND_ * H_;
    const u16* wo_i = wo_bf + (size_t)i * H_ * ND_;
    const u16* sk_i = swk_bf + (size_t)i * ND_ * H_;

    k_layernorm_bf<<<dim3(B_ * L_ / 4), 256, 0, stream>>>(nodes, ln_s + i * H_, ln_b + i * H_,
                                                          mask, xn_bf, i > 0 ? 1 : 0);
    // rk, rv, rq (fp32) + kkb_sw row 0 (bf16) — all read iteration-start relay
    k_matvec4<<<dim3(256, B_, 4), 256, 0, stream>>>(
        rwk + (size_t)i * ND_ * H_, rwk_b + i * ND_, rk,
        rwv + (size_t)i * ND_ * H_, rwv_b + i * ND_, rv,
        swq + (size_t)i * ND_ * H_, swq_b + i * ND_, rq,
        swk + (size_t)i * ND_ * H_, swk_b + i * ND_, kkb_sw, relay);
    k_gemm5<<<dim3(32, 40), 256, 0, stream>>>(wq_i, wk_i, wv_i,
                                              rwq_b + i * ND_, rwk_b + i * ND_, rwv_b + i * ND_,
                                              xn_bf, embs_bf, qkv5_bf);
    k_msa1<<<dim3(L_ / 4, 1, B_), 256, 0, stream>>>(qkv5_bf, qkv5_bf + SZ, qkv5_bf + 2 * SZ,
                                                    qkv5_bf + 3 * SZ, qkv5_bf + 4 * SZ, rk, rv, att_bf);
    k_gemm_wo_s<<<dim3(32, 16), 256, 0, stream>>>(wo_i, rwo_b + i * H_, att_bf, nodes, nodes_bf);
    k_gemm_kkb_sw<<<dim3(32, 16), 256, 0, stream>>>(sk_i, swk_b + i * ND_, nodes_bf, kkb_sw);
    k_msa2f<<<dim3(17, B_), 256, 0, stream>>>(kkb_sw, rq, mask, avp, Ep);
    k_msa2r<<<dim3(4, B_), 256, 0, stream>>>(avp, Ep, satt);
    k_matvec<<<dim3(256, B_), 256, 0, stream>>>(swo + (size_t)i * H_ * ND_, swo_b + i * H_,
                                                satt, relay, 1);
  }
  k_final<<<4096, 256, 0, stream>>>(nodes, mask, out);
  k_copy_relay<<<dim3((B_ * H_) / 256), 256, 0, stream>>>(relay, out + (size_t)B_ * L_ * H_);
}

// Round 15
// 617.193 us; speedup vs baseline: 1.4039x; 1.4039x over previous
//
#include <hip/hip_runtime.h>
#include <math.h>

namespace {

constexpr int B_ = 4, L_ = 1024, H_ = 1024, NH_ = 16, HD_ = 64, ND_ = 1024, ITERS_ = 4;

typedef unsigned short u16;
typedef __attribute__((ext_vector_type(8))) short short8;
typedef __attribute__((ext_vector_type(4))) float f32x4;

__device__ inline u16 f2bf(float f) {
  unsigned u = __builtin_bit_cast(unsigned, f);
  u += 0x7FFFu + ((u >> 16) & 1u);
  return (u16)(u >> 16);
}
__device__ inline float bf2f(u16 v) {
  unsigned u = ((unsigned)v) << 16;
  return __builtin_bit_cast(float, u);
}

__device__ inline void gl_lds16(const u16* g, u16* l) {
  __builtin_amdgcn_global_load_lds((const __attribute__((address_space(1))) void*)g,
                                   (__attribute__((address_space(3))) void*)l, 16, 0, 0);
}

// ---------- prep: 6 f2bf conversions + nodes copy ----------
__global__ void k_prep(const float* __restrict__ data, const float* __restrict__ rwq,
                       const float* __restrict__ rwk, const float* __restrict__ rwv,
                       const float* __restrict__ rwo, const float* __restrict__ swk,
                       u16* __restrict__ embs_bf, u16* __restrict__ wq_bf,
                       u16* __restrict__ wk_bf, u16* __restrict__ wv_bf,
                       u16* __restrict__ wo_bf, u16* __restrict__ swk_bf,
                       float* __restrict__ nodes) {
  int i = blockIdx.x * 256 + threadIdx.x;
  int which = blockIdx.y;
  if (which == 6) {
    reinterpret_cast<float4*>(nodes)[i] = reinterpret_cast<const float4*>(data)[i];
    return;
  }
  const float* src;
  u16* dst;
  switch (which) {
    case 0: src = data; dst = embs_bf; break;
    case 1: src = rwq; dst = wq_bf; break;
    case 2: src = rwk; dst = wk_bf; break;
    case 3: src = rwv; dst = wv_bf; break;
    case 4: src = rwo; dst = wo_bf; break;
    default: src = swk; dst = swk_bf; break;
  }
  float4 v = reinterpret_cast<const float4*>(src)[i];
  ushort4 o;
  o.x = f2bf(v.x); o.y = f2bf(v.y); o.z = f2bf(v.z); o.w = f2bf(v.w);
  reinterpret_cast<ushort4*>(dst)[i] = o;
}

// ---------- relay init ----------
__global__ void k_relay_part(const float* __restrict__ data, float* __restrict__ part) {
  int b = blockIdx.z, chunk = blockIdx.y;
  int c = blockIdx.x * 256 + threadIdx.x;
  const float* p = data + ((size_t)b * L_ + chunk * 128) * H_ + c;
  float acc = 0.f;
  for (int l = 0; l < 128; ++l) acc += p[(size_t)l * H_];
  part[((size_t)b * 8 + chunk) * H_ + c] = acc;
}
__global__ void k_relay_reduce(const float* __restrict__ part, float* __restrict__ relay) {
  int i = blockIdx.x * 256 + threadIdx.x;
  int b = i >> 10, c = i & 1023;
  float acc = 0.f;
  for (int j = 0; j < 8; ++j) acc += part[((size_t)b * 8 + j) * H_ + c];
  relay[i] = acc * (1.f / (float)L_);
}

// ---------- LayerNorm rows of nodes [B,L,H]; fused pad-row zeroing ----------
__global__ __launch_bounds__(256) void k_layernorm_bf(float* __restrict__ nodes,
                                                      const float* __restrict__ s,
                                                      const float* __restrict__ bb,
                                                      const int* __restrict__ mask,
                                                      u16* __restrict__ y, int do_zero) {
  int row = blockIdx.x * 4 + (threadIdx.x >> 6);
  int lane = threadIdx.x & 63;
  int b = row >> 10, l = row & 1023;
  bool pad = do_zero && (mask[b * L_ + l] == 0);
  float4* xr = reinterpret_cast<float4*>(nodes + (size_t)row * H_);
  float4 v[4];
  float sum = 0.f, sq = 0.f;
#pragma unroll
  for (int j = 0; j < 4; ++j) {
    v[j] = pad ? float4{0.f, 0.f, 0.f, 0.f} : xr[lane + 64 * j];
    sum += v[j].x + v[j].y + v[j].z + v[j].w;
    sq += v[j].x * v[j].x + v[j].y * v[j].y + v[j].z * v[j].z + v[j].w * v[j].w;
  }
  if (pad) {
#pragma unroll
    for (int j = 0; j < 4; ++j) xr[lane + 64 * j] = float4{0.f, 0.f, 0.f, 0.f};
  }
#pragma unroll
  for (int off = 32; off; off >>= 1) {
    sum += __shfl_xor(sum, off);
    sq += __shfl_xor(sq, off);
  }
  float mu = sum * (1.f / (float)H_);
  float rstd = rsqrtf(sq * (1.f / (float)H_) - mu * mu + 1e-5f);
  ushort4* yr = reinterpret_cast<ushort4*>(y + (size_t)row * H_);
#pragma unroll
  for (int j = 0; j < 4; ++j) {
    int c4 = lane + 64 * j;
    float4 sc = reinterpret_cast<const float4*>(s)[c4];
    float4 bc = reinterpret_cast<const float4*>(bb)[c4];
    ushort4 o;
    o.x = f2bf((v[j].x - mu) * rstd * sc.x + bc.x);
    o.y = f2bf((v[j].y - mu) * rstd * sc.y + bc.y);
    o.z = f2bf((v[j].z - mu) * rstd * sc.z + bc.z);
    o.w = f2bf((v[j].w - mu) * rstd * sc.w + bc.w);
    yr[c4] = o;
  }
}

// ================= 128x128 MFMA GEMM, BK=64 (gemm5) =================

#define GEMM_PROLOGUE(XPTR, WPTR)                                              \
  __shared__ __align__(16) u16 sX[2][128 * 32];                                \
  __shared__ __align__(16) u16 sW[2][128 * 32];                                \
  const int t = threadIdx.x;                                                   \
  const int w = t >> 6, lane = t & 63;                                         \
  const int wm = w >> 1, wn = w & 1;                                           \
  const int r4 = lane >> 2, slot = lane & 3;                                   \
  const int rowS0 = w * 16 + r4, rowS1 = 64 + rowS0;                           \
  const int colS0 = ((slot ^ ((rowS0 >> 1) & 3)) << 3);                        \
  const int colS1 = ((slot ^ ((rowS1 >> 1) & 3)) << 3);                        \
  const u16* gX0 = (XPTR) + (size_t)(bm + rowS0) * 1024 + colS0;               \
  const u16* gX1 = (XPTR) + (size_t)(bm + rowS1) * 1024 + colS1;               \
  const u16* gW0 = (WPTR) + (size_t)(bn + rowS0) * 1024 + colS0;               \
  const u16* gW1 = (WPTR) + (size_t)(bn + rowS1) * 1024 + colS1;               \
  u16* lX0a = sX[0] + w * 512;                                                 \
  u16* lX0b = sX[1] + w * 512;                                                 \
  u16* lX1a = sX[0] + (4 + w) * 512;                                           \
  u16* lX1b = sX[1] + (4 + w) * 512;                                           \
  u16* lW0a = sW[0] + w * 512;                                                 \
  u16* lW0b = sW[1] + w * 512;                                                 \
  u16* lW1a = sW[0] + (4 + w) * 512;                                           \
  u16* lW1b = sW[1] + (4 + w) * 512;                                           \
  const int kidx = (((lane >> 4) ^ ((lane >> 1) & 3)) << 3);                   \
  f32x4 acc[4][4];                                                             \
  _Pragma("unroll") for (int i_ = 0; i_ < 4; ++i_)                             \
      _Pragma("unroll") for (int j_ = 0; j_ < 4; ++j_)                         \
          acc[i_][j_] = f32x4{0.f, 0.f, 0.f, 0.f};

#define GEMM_KLOOP64(AROWBASE, BROWBASE, ASRC, BSRC)                           \
  for (int ck = 0; ck < 1024; ck += 64) {                                      \
    gl_lds16(gX0, lX0a);                                                       \
    gl_lds16(gX0 + 32, lX0b);                                                  \
    gl_lds16(gX1, lX1a);                                                       \
    gl_lds16(gX1 + 32, lX1b);                                                  \
    gl_lds16(gW0, lW0a);                                                       \
    gl_lds16(gW0 + 32, lW0b);                                                  \
    gl_lds16(gW1, lW1a);                                                       \
    gl_lds16(gW1 + 32, lW1b);                                                  \
    gX0 += 64; gX1 += 64; gW0 += 64; gW1 += 64;                                \
    __syncthreads();                                                           \
    _Pragma("unroll") for (int h = 0; h < 2; ++h) {                            \
      short8 af_[4], bf_[4];                                                   \
      _Pragma("unroll") for (int mf = 0; mf < 4; ++mf)                         \
          af_[mf] = *reinterpret_cast<const short8*>(                          \
              &ASRC[h][((AROWBASE) + mf * 16) * 32 + kidx]);                   \
      _Pragma("unroll") for (int nf = 0; nf < 4; ++nf)                         \
          bf_[nf] = *reinterpret_cast<const short8*>(                          \
              &BSRC[h][((BROWBASE) + nf * 16) * 32 + kidx]);                   \
      _Pragma("unroll") for (int mf = 0; mf < 4; ++mf)                         \
          _Pragma("unroll") for (int nf = 0; nf < 4; ++nf)                     \
              acc[mf][nf] = __builtin_amdgcn_mfma_f32_16x16x32_bf16(           \
                  af_[mf], bf_[nf], acc[mf][nf], 0, 0, 0);                     \
    }                                                                          \
    __syncthreads();                                                          \
  }

// ---- 5-in-1 GEMM, swapped orientation (A=W -> M=o, B=X -> N=l(B*L)) ----
__global__ __launch_bounds__(256, 3) void k_gemm5(const u16* __restrict__ wq,
                                                  const u16* __restrict__ wk,
                                                  const u16* __restrict__ wv,
                                                  const float* __restrict__ bq,
                                                  const float* __restrict__ bk,
                                                  const float* __restrict__ bv,
                                                  const u16* __restrict__ xn,
                                                  const u16* __restrict__ embs,
                                                  u16* __restrict__ Y) {
  const int bm = blockIdx.x * 128;            // bl rows
  const int which = blockIdx.y >> 3;
  const int bn = (blockIdx.y & 7) * 128;      // o
  const u16* W = (which == 0) ? wq : ((which == 1 || which == 3) ? wk : wv);
  const float* bias = (which == 0) ? bq : ((which == 1 || which == 3) ? bk : bv);
  const u16* X = (which < 3) ? xn : embs;
  u16* Yw = Y + (size_t)which * ((size_t)B_ * L_ * ND_);

  GEMM_PROLOGUE(X, W)
  const int rW = wm * 64 + (lane & 15);
  const int rX = wn * 64 + (lane & 15);
  GEMM_KLOOP64(rW, rX, sW, sX)

#pragma unroll
  for (int mo = 0; mo < 4; ++mo) {
    int o0 = bn + wm * 64 + mo * 16 + ((lane >> 4) << 2);
    float4 bs = *reinterpret_cast<const float4*>(bias + o0);
#pragma unroll
    for (int nl = 0; nl < 4; ++nl) {
      int bl = bm + wn * 64 + nl * 16 + (lane & 15);
      f32x4 vv = acc[mo][nl];
      ushort4 ov;
      ov.x = f2bf(vv[0] + bs.x);
      ov.y = f2bf(vv[1] + bs.y);
      ov.z = f2bf(vv[2] + bs.z);
      ov.w = f2bf(vv[3] + bs.w);
      *reinterpret_cast<ushort4*>(&Yw[(size_t)bl * 1024 + o0]) = ov;
    }
  }
}

// ================= 64(o) x 128(bl) GEMM bodies (wo / kkb_sw), BK=64 =================

#define SMALL_PROLOGUE(XPTR, WPTR)                                             \
  __shared__ __align__(16) u16 sX[2][128 * 32];                                \
  __shared__ __align__(16) u16 sW[2][64 * 32];                                 \
  const int t = threadIdx.x;                                                   \
  const int w = t >> 6, lane = t & 63;                                         \
  const int wm = w >> 1, wn = w & 1;                                           \
  const int r4 = lane >> 2, slot = lane & 3;                                   \
  const int rowS0 = w * 16 + r4, rowS1 = 64 + rowS0;                           \
  const int colS0 = ((slot ^ ((rowS0 >> 1) & 3)) << 3);                        \
  const int colS1 = ((slot ^ ((rowS1 >> 1) & 3)) << 3);                        \
  const u16* gX0 = (XPTR) + (size_t)(bm + rowS0) * 1024 + colS0;               \
  const u16* gX1 = (XPTR) + (size_t)(bm + rowS1) * 1024 + colS1;               \
  const u16* gW0 = (WPTR) + (size_t)(bn + rowS0) * 1024 + colS0;               \
  u16* lX0a = sX[0] + w * 512;                                                 \
  u16* lX0b = sX[1] + w * 512;                                                 \
  u16* lX1a = sX[0] + (4 + w) * 512;                                           \
  u16* lX1b = sX[1] + (4 + w) * 512;                                           \
  u16* lW0a = sW[0] + w * 512;                                                 \
  u16* lW0b = sW[1] + w * 512;                                                 \
  const int kidx = (((lane >> 4) ^ ((lane >> 1) & 3)) << 3);

#define SMALL_KLOOP(MFN, NFN, ACC, AROWBASE, BROWBASE, ASRC, BSRC)             \
  for (int ck = 0; ck < 1024; ck += 64) {                                      \
    gl_lds16(gX0, lX0a);                                                       \
    gl_lds16(gX0 + 32, lX0b);                                                  \
    gl_lds16(gX1, lX1a);                                                       \
    gl_lds16(gX1 + 32, lX1b);                                                  \
    gl_lds16(gW0, lW0a);                                                       \
    gl_lds16(gW0 + 32, lW0b);                                                  \
    gX0 += 64; gX1 += 64; gW0 += 64;                                           \
    __syncthreads();                                                           \
    _Pragma("unroll") for (int h = 0; h < 2; ++h) {                            \
      short8 af_[MFN], bf_[NFN];                                               \
      _Pragma("unroll") for (int mf = 0; mf < MFN; ++mf)                       \
          af_[mf] = *reinterpret_cast<const short8*>(                          \
              &ASRC[h][((AROWBASE) + mf * 16) * 32 + kidx]);                   \
      _Pragma("unroll") for (int nf = 0; nf < NFN; ++nf)                       \
          bf_[nf] = *reinterpret_cast<const short8*>(                          \
              &BSRC[h][((BROWBASE) + nf * 16) * 32 + kidx]);                   \
      _Pragma("unroll") for (int mf = 0; mf < MFN; ++mf)                       \
          _Pragma("unroll") for (int nf = 0; nf < NFN; ++nf)                   \
              ACC[mf][nf] = __builtin_amdgcn_mfma_f32_16x16x32_bf16(           \
                  af_[mf], bf_[nf], ACC[mf][nf], 0, 0, 0);                     \
    }                                                                          \
    __syncthreads();                                                          \
  }

// ---- Wo GEMM (swapped: A=W M=o 64, B=X N=bl 128); grid (32, 16) ----
__global__ __launch_bounds__(256, 2) void k_gemm_wo_s(const u16* __restrict__ W,
                                                      const float* __restrict__ bias,
                                                      const u16* __restrict__ X,
                                                      float* __restrict__ nodes,
                                                      u16* __restrict__ nodes_bf) {
  const int bm = blockIdx.x * 128;  // bl
  const int bn = blockIdx.y * 64;   // o
  SMALL_PROLOGUE(X, W)
  f32x4 acc[2][4];
#pragma unroll
  for (int i_ = 0; i_ < 2; ++i_)
#pragma unroll
    for (int j_ = 0; j_ < 4; ++j_) acc[i_][j_] = f32x4{0.f, 0.f, 0.f, 0.f};
  const int rW = wm * 32 + (lane & 15);
  const int rX = wn * 64 + (lane & 15);
  SMALL_KLOOP(2, 4, acc, rW, rX, sW, sX)

#pragma unroll
  for (int mo = 0; mo < 2; ++mo) {
    int o0 = bn + wm * 32 + mo * 16 + ((lane >> 4) << 2);
    float4 bs = *reinterpret_cast<const float4*>(bias + o0);
#pragma unroll
    for (int nl = 0; nl < 4; ++nl) {
      int bl = bm + wn * 64 + nl * 16 + (lane & 15);
      size_t ni = (size_t)bl * 1024 + o0;
      float4 curv = *reinterpret_cast<const float4*>(&nodes[ni]);
      f32x4 vv = acc[mo][nl];
      float r0 = vv[0] + bs.x; r0 = curv.x + (r0 > 0.f ? r0 : 0.01f * r0);
      float r1 = vv[1] + bs.y; r1 = curv.y + (r1 > 0.f ? r1 : 0.01f * r1);
      float r2 = vv[2] + bs.z; r2 = curv.z + (r2 > 0.f ? r2 : 0.01f * r2);
      float r3 = vv[3] + bs.w; r3 = curv.w + (r3 > 0.f ? r3 : 0.01f * r3);
      *reinterpret_cast<float4*>(&nodes[ni]) = float4{r0, r1, r2, r3};
      ushort4 ov;
      ov.x = f2bf(r0); ov.y = f2bf(r1); ov.z = f2bf(r2); ov.w = f2bf(r3);
      *reinterpret_cast<ushort4*>(&nodes_bf[ni]) = ov;
    }
  }
}

// ---- kkb GEMM swapped: out bf16 [b][1+l][o]; grid (32, 16) ----
__global__ __launch_bounds__(256, 2) void k_gemm_kkb_sw(const u16* __restrict__ W,
                                                        const float* __restrict__ bias,
                                                        const u16* __restrict__ X,
                                                        u16* __restrict__ Y) {
  const int bm = blockIdx.x * 128;  // bl
  const int bn = blockIdx.y * 64;   // o
  SMALL_PROLOGUE(X, W)
  f32x4 acc[2][4];
#pragma unroll
  for (int i_ = 0; i_ < 2; ++i_)
#pragma unroll
    for (int j_ = 0; j_ < 4; ++j_) acc[i_][j_] = f32x4{0.f, 0.f, 0.f, 0.f};
  const int rW = wm * 32 + (lane & 15);
  const int rX = wn * 64 + (lane & 15);
  SMALL_KLOOP(2, 4, acc, rW, rX, sW, sX)

#pragma unroll
  for (int mo = 0; mo < 2; ++mo) {
    int o0 = bn + wm * 32 + mo * 16 + ((lane >> 4) << 2);
    float4 bs = *reinterpret_cast<const float4*>(bias + o0);
#pragma unroll
    for (int nl = 0; nl < 4; ++nl) {
      int bl = bm + wn * 64 + nl * 16 + (lane & 15);
      size_t row = (size_t)(bl >> 10) * 1025 + 1 + (bl & 1023);
      f32x4 vv = acc[mo][nl];
      ushort4 ov;
      ov.x = f2bf(vv[0] + bs.x);
      ov.y = f2bf(vv[1] + bs.y);
      ov.z = f2bf(vv[2] + bs.z);
      ov.w = f2bf(vv[3] + bs.w);
      *reinterpret_cast<ushort4*>(&Y[row * 1024 + o0]) = ov;
    }
  }
}

// ---------- quad matvec: rk, rv, rq (fp32) and kkb_sw row 0 (bf16) ----------
__global__ __launch_bounds__(256) void k_matvec4(const float* __restrict__ W0,
                                                 const float* __restrict__ b0, float* __restrict__ y0,
                                                 const float* __restrict__ W1,
                                                 const float* __restrict__ b1, float* __restrict__ y1,
                                                 const float* __restrict__ W2,
                                                 const float* __restrict__ b2, float* __restrict__ y2,
                                                 const float* __restrict__ W3,
                                                 const float* __restrict__ b3, u16* __restrict__ y3b,
                                                 const float* __restrict__ x) {
  int b = blockIdx.y, z = blockIdx.z;
  const float* W = (z == 0) ? W0 : (z == 1) ? W1 : (z == 2) ? W2 : W3;
  const float* bias = (z == 0) ? b0 : (z == 1) ? b1 : (z == 2) ? b2 : b3;
  int o = blockIdx.x * 4 + (threadIdx.x >> 6);
  int lane = threadIdx.x & 63;
  const float* wr = W + (size_t)o * 1024;
  const float* xb = x + (size_t)b * 1024;
  float acc = 0.f;
  for (int c = lane; c < 1024; c += 64) acc += wr[c] * xb[c];
#pragma unroll
  for (int off = 32; off; off >>= 1) acc += __shfl_xor(acc, off);
  if (lane == 0) {
    acc += bias[o];
    if (z == 3) y3b[(size_t)b * 1025 * 1024 + o] = f2bf(acc);
    else if (z == 2) y2[(size_t)b * 1024 + o] = acc;
    else if (z == 1) y1[(size_t)b * 1024 + o] = acc;
    else y0[(size_t)b * 1024 + o] = acc;
  }
}

// ---------- single matvec ----------
__global__ __launch_bounds__(256) void k_matvec(const float* __restrict__ W,
                                                const float* __restrict__ bias,
                                                const float* __restrict__ x,
                                                float* __restrict__ y, int leaky) {
  int b = blockIdx.y;
  int o = blockIdx.x * 4 + (threadIdx.x >> 6);
  int lane = threadIdx.x & 63;
  const float* wr = W + (size_t)o * 1024;
  const float* xb = x + (size_t)b * 1024;
  float acc = 0.f;
  for (int c = lane; c < 1024; c += 64) acc += wr[c] * xb[c];
#pragma unroll
  for (int off = 32; off; off >>= 1) acc += __shfl_xor(acc, off);
  if (lane == 0) {
    acc += bias[o];
    if (leaky) acc = acc > 0.f ? acc : 0.01f * acc;
    y[(size_t)b * 1024 + o] = acc;
  }
}

// ---------- msa1 ring attention: 16 d per thread, 4 l per block ----------
__global__ __launch_bounds__(256) void k_msa1(const u16* __restrict__ q,
                                              const u16* __restrict__ k,
                                              const u16* __restrict__ v,
                                              const u16* __restrict__ ke,
                                              const u16* __restrict__ ve,
                                              const float* __restrict__ rk,
                                              const float* __restrict__ rv,
                                              u16* __restrict__ attbf) {
  int t = threadIdx.x;
  int wv = t >> 6, lane = t & 63;
  int head = lane >> 2, dq = lane & 3;
  int l = blockIdx.x * 4 + wv;
  int b = blockIdx.z;
  size_t row = ((size_t)(b * 1024 + l)) * 1024 + head * 64 + dq * 16;
  size_t rbase = (size_t)b * 1024 + head * 64 + dq * 16;

  float qf[16];
  {
    const short8* qp = reinterpret_cast<const short8*>(q + row);
#pragma unroll
    for (int j = 0; j < 2; ++j) {
      short8 qv = qp[j];
#pragma unroll
      for (int e = 0; e < 8; ++e) qf[j * 8 + e] = bf2f((u16)qv[e]);
    }
  }
  float s[7];
#pragma unroll
  for (int u = 0; u < 5; ++u) {
    int lk = l + u - 2;
    float su = 0.f;
    if (lk >= 0 && lk < L_) {
      const short8* kp = reinterpret_cast<const short8*>(
          k + ((size_t)(b * 1024 + lk)) * 1024 + head * 64 + dq * 16);
#pragma unroll
      for (int j = 0; j < 2; ++j) {
        short8 kv = kp[j];
#pragma unroll
        for (int e = 0; e < 8; ++e) su = fmaf(qf[j * 8 + e], bf2f((u16)kv[e]), su);
      }
    }
    s[u] = su;
  }
  {
    float su = 0.f;
    const short8* kp = reinterpret_cast<const short8*>(ke + row);
#pragma unroll
    for (int j = 0; j < 2; ++j) {
      short8 kv = kp[j];
#pragma unroll
      for (int e = 0; e < 8; ++e) su = fmaf(qf[j * 8 + e], bf2f((u16)kv[e]), su);
    }
    s[5] = su;
  }
  {
    float su = 0.f;
    const float4* rp = reinterpret_cast<const float4*>(rk + rbase);
#pragma unroll
    for (int j = 0; j < 4; ++j) {
      float4 r4 = rp[j];
      su = fmaf(qf[j * 4 + 0], r4.x, su);
      su = fmaf(qf[j * 4 + 1], r4.y, su);
      su = fmaf(qf[j * 4 + 2], r4.z, su);
      su = fmaf(qf[j * 4 + 3], r4.w, su);
    }
    s[6] = su;
  }
#pragma unroll
  for (int u = 0; u < 7; ++u) {
    s[u] += __shfl_xor(s[u], 1);
    s[u] += __shfl_xor(s[u], 2);
  }
  float m = -1e30f;
#pragma unroll
  for (int u = 0; u < 7; ++u) {
    s[u] *= 0.125f;
    m = fmaxf(m, s[u]);
  }
  float e[7], tot = 0.f;
#pragma unroll
  for (int u = 0; u < 7; ++u) {
    e[u] = expf(s[u] - m);
    tot += e[u];
  }
  float inv = 1.f / tot;
#pragma unroll
  for (int u = 0; u < 7; ++u) e[u] *= inv;

  float av[16];
  {
    const float4* rp = reinterpret_cast<const float4*>(rv + rbase);
#pragma unroll
    for (int j = 0; j < 4; ++j) {
      float4 r4 = rp[j];
      av[j * 4 + 0] = e[6] * r4.x;
      av[j * 4 + 1] = e[6] * r4.y;
      av[j * 4 + 2] = e[6] * r4.z;
      av[j * 4 + 3] = e[6] * r4.w;
    }
  }
  {
    const short8* vp = reinterpret_cast<const short8*>(ve + row);
#pragma unroll
    for (int j = 0; j < 2; ++j) {
      short8 vvv = vp[j];
#pragma unroll
      for (int ee = 0; ee < 8; ++ee) av[j * 8 + ee] = fmaf(e[5], bf2f((u16)vvv[ee]), av[j * 8 + ee]);
    }
  }
#pragma unroll
  for (int u = 0; u < 5; ++u) {
    int lk = l + u - 2;
    if (lk >= 0 && lk < L_) {
      const short8* vp = reinterpret_cast<const short8*>(
          v + ((size_t)(b * 1024 + lk)) * 1024 + head * 64 + dq * 16);
#pragma unroll
      for (int j = 0; j < 2; ++j) {
        short8 vvv = vp[j];
#pragma unroll
        for (int ee = 0; ee < 8; ++ee) av[j * 8 + ee] = fmaf(e[u], bf2f((u16)vvv[ee]), av[j * 8 + ee]);
      }
    }
  }
  u16 ob[16];
#pragma unroll
  for (int j = 0; j < 16; ++j) ob[j] = f2bf(av[j]);
  uint4* d4 = reinterpret_cast<uint4*>(attbf + row);
  const uint4* s4 = reinterpret_cast<const uint4*>(ob);
  d4[0] = s4[0];
  d4[1] = s4[1];
}

// ---------- msa2 flash-style: wave per 16-position chunk (v = k, faithful) ----------
__global__ __launch_bounds__(256) void k_msa2f(const u16* __restrict__ kkb,
                                               const float* __restrict__ rq,
                                               const int* __restrict__ mask,
                                               float* __restrict__ avp,
                                               float* __restrict__ Ep) {
  int b = blockIdx.y;
  int w = threadIdx.x >> 6, lane = threadIdx.x & 63;
  int wc = blockIdx.x * 4 + w;  // 0..67
  int q4 = lane & 3;
  int ch0 = lane * 16;
  float rqv[16];
  {
    const float4* rp = reinterpret_cast<const float4*>(rq + (size_t)b * 1024 + ch0);
#pragma unroll
    for (int j = 0; j < 4; ++j) {
      float4 v4 = rp[j];
      rqv[j * 4 + 0] = v4.x; rqv[j * 4 + 1] = v4.y;
      rqv[j * 4 + 2] = v4.z; rqv[j * 4 + 3] = v4.w;
    }
  }
  float av[16];
#pragma unroll
  for (int j = 0; j < 16; ++j) av[j] = 0.f;
  float eacc = 0.f;
  int p0 = wc * 16;
  int pend = p0 + 16;
  if (pend > 1025) pend = 1025;
  for (int p = p0; p < pend; ++p) {
    if (p > 0 && mask[b * L_ + p - 1] == 0) continue;  // wave-uniform
    const uint4* kr = reinterpret_cast<const uint4*>(kkb + ((size_t)b * 1025 + p) * 1024 + ch0);
    uint4 ka = kr[0], kb2 = kr[1];
    float kf[16];
    const u16* kp = reinterpret_cast<const u16*>(&ka);
#pragma unroll
    for (int j = 0; j < 8; ++j) kf[j] = bf2f(kp[j]);
    const u16* kp2 = reinterpret_cast<const u16*>(&kb2);
#pragma unroll
    for (int j = 0; j < 8; ++j) kf[8 + j] = bf2f(kp2[j]);
    float s = 0.f;
#pragma unroll
    for (int j = 0; j < 16; ++j) s = fmaf(rqv[j], kf[j], s);
    s += __shfl_xor(s, 1);
    s += __shfl_xor(s, 2);
    float e = expf(s * 0.125f);
    if (q4 == 0) eacc += e;
#pragma unroll
    for (int j = 0; j < 16; ++j) av[j] = fmaf(e, kf[j], av[j]);
  }
  float* ap = avp + ((size_t)b * 68 + wc) * 1024 + ch0;
#pragma unroll
  for (int j = 0; j < 4; ++j)
    reinterpret_cast<float4*>(ap)[j] =
        float4{av[j * 4 + 0], av[j * 4 + 1], av[j * 4 + 2], av[j * 4 + 3]};
  if (q4 == 0) Ep[((size_t)b * 68 + wc) * 16 + (lane >> 2)] = eacc;
}

// ---------- msa2 reduce: satt = (sum avp) / (sum Ep) ----------
__global__ void k_msa2r(const float* __restrict__ avp, const float* __restrict__ Ep,
                        float* __restrict__ satt) {
  int b = blockIdx.y;
  int idx = blockIdx.x * 256 + threadIdx.x;  // 0..1023
  int head = idx >> 6;
  float a = 0.f, E = 0.f;
  for (int k = 0; k < 68; ++k) a += avp[((size_t)b * 68 + k) * 1024 + idx];
  for (int k = 0; k < 68; ++k) E += Ep[((size_t)b * 68 + k) * 16 + head];
  satt[(size_t)b * 1024 + idx] = a / E;
}

// ---------- final: out = pad ? 0 : nodes ----------
__global__ void k_final(const float* __restrict__ nodes, const int* __restrict__ mask,
                        float* __restrict__ out) {
  int i = blockIdx.x * 256 + threadIdx.x;
  int row = i >> 8;
  int b = row >> 10, l = row & 1023;
  float4 v = (mask[b * L_ + l] == 0) ? float4{0.f, 0.f, 0.f, 0.f}
                                     : reinterpret_cast<const float4*>(nodes)[i];
  reinterpret_cast<float4*>(out)[i] = v;
}

__global__ void k_copy_relay(const float* __restrict__ relay, float* __restrict__ out) {
  int i = blockIdx.x * 256 + threadIdx.x;
  out[i] = relay[i];
}

}  // namespace

extern "C" void kernel_launch(void* const* d_in, const int* in_sizes, int n_in,
                              void* d_out, int out_size, void* d_ws, size_t ws_size,
                              hipStream_t stream) {
  (void)in_sizes; (void)n_in; (void)out_size; (void)ws_size;
  const float* data = (const float*)d_in[0];
  const int* mask = (const int*)d_in[1];
  const float* ln_s = (const float*)d_in[2];
  const float* ln_b = (const float*)d_in[3];
  const float* rwq = (const float*)d_in[4];
  const float* rwq_b = (const float*)d_in[5];
  const float* rwk = (const float*)d_in[6];
  const float* rwk_b = (const float*)d_in[7];
  const float* rwv = (const float*)d_in[8];
  const float* rwv_b = (const float*)d_in[9];
  const float* rwo = (const float*)d_in[10];
  const float* rwo_b = (const float*)d_in[11];
  const float* swq = (const float*)d_in[12];
  const float* swq_b = (const float*)d_in[13];
  const float* swk = (const float*)d_in[14];
  const float* swk_b = (const float*)d_in[15];
  const float* swo = (const float*)d_in[16];
  const float* swo_b = (const float*)d_in[17];
  float* out = (float*)d_out;

  const size_t SZ = (size_t)B_ * ND_ * L_;  // 4M elements
  float* f = (float*)d_ws;
  float* nodes = f; f += SZ;                       // fp32 [B,L,H]
  float* part = f; f += (size_t)B_ * 8 * H_;
  float* relay = f; f += B_ * H_;
  float* rk = f; f += B_ * ND_;
  float* rv = f; f += B_ * ND_;
  float* rq = f; f += B_ * ND_;
  float* satt = f; f += B_ * ND_;
  float* avp = f; f += (size_t)B_ * 68 * 1024;
  float* Ep = f; f += (size_t)B_ * 68 * 16;
  u16* u = (u16*)f;
  u16* xn_bf = u; u += SZ;       // [B,L,H]
  u16* embs_bf = u; u += SZ;     // [B,L,H]
  u16* att_bf = u; u += SZ;      // [B,L,ND]
  u16* nodes_bf = u; u += SZ;    // [B,L,H]
  u16* kkb_sw = u; u += (size_t)B_ * 1025 * 1024;  // bf16 [b][p][o]
  u16* qkv5_bf = u; u += 5 * SZ; // [5][B,L,ND]: q,k,v,ke,ve
  u16* wq_bf = u; u += SZ;
  u16* wk_bf = u; u += SZ;
  u16* wv_bf = u; u += SZ;
  u16* wo_bf = u; u += SZ;
  u16* swk_bf = u; u += SZ;

  k_prep<<<dim3(4096, 7), 256, 0, stream>>>(data, rwq, rwk, rwv, rwo, swk,
                                            embs_bf, wq_bf, wk_bf, wv_bf, wo_bf, swk_bf, nodes);
  k_relay_part<<<dim3(H_ / 256, 8, B_), 256, 0, stream>>>(data, part);
  k_relay_reduce<<<dim3((B_ * H_) / 256), 256, 0, stream>>>(part, relay);

  for (int i = 0; i < ITERS_; ++i) {
    const u16* wq_i = wq_bf + (size_t)i * ND_ * H_;
    const u16* wk_i = wk_bf + (size_t)i * ND_ * H_;
    const u16* wv_i = wv_bf + (size_t)i * ND_ * H_;
    const u16* wo_i = wo_bf + (size_t)i * H_ * ND_;
    const u16* sk_i = swk_bf + (size_t)i * ND_ * H_;

    k_layernorm_bf<<<dim3(B_ * L_ / 4), 256, 0, stream>>>(nodes, ln_s + i * H_, ln_b + i * H_,
                                                          mask, xn_bf, i > 0 ? 1 : 0);
    // rk, rv, rq (fp32) + kkb_sw row 0 (bf16) — all read iteration-start relay
    k_matvec4<<<dim3(256, B_, 4), 256, 0, stream>>>(
        rwk + (size_t)i * ND_ * H_, rwk_b + i * ND_, rk,
        rwv + (size_t)i * ND_ * H_, rwv_b + i * ND_, rv,
        swq + (size_t)i * ND_ * H_, swq_b + i * ND_, rq,
        swk + (size_t)i * ND_ * H_, swk_b + i * ND_, kkb_sw, relay);
    k_gemm5<<<dim3(32, 40), 256, 0, stream>>>(wq_i, wk_i, wv_i,
                                              rwq_b + i * ND_, rwk_b + i * ND_, rwv_b + i * ND_,
                                              xn_bf, embs_bf, qkv5_bf);
    k_msa1<<<dim3(L_ / 4, 1, B_), 256, 0, stream>>>(qkv5_bf, qkv5_bf + SZ, qkv5_bf + 2 * SZ,
                                                    qkv5_bf + 3 * SZ, qkv5_bf + 4 * SZ, rk, rv, att_bf);
    k_gemm_wo_s<<<dim3(32, 16), 256, 0, stream>>>(wo_i, rwo_b + i * H_, att_bf, nodes, nodes_bf);
    k_gemm_kkb_sw<<<dim3(32, 16), 256, 0, stream>>>(sk_i, swk_b + i * ND_, nodes_bf, kkb_sw);
    k_msa2f<<<dim3(17, B_), 256, 0, stream>>>(kkb_sw, rq, mask, avp, Ep);
    k_msa2r<<<dim3(4, B_), 256, 0, stream>>>(avp, Ep, satt);
    k_matvec<<<dim3(256, B_), 256, 0, stream>>>(swo + (size_t)i * H_ * ND_, swo_b + i * H_,
                                                satt, relay, 1);
  }
  k_final<<<4096, 256, 0, stream>>>(nodes, mask, out);
  k_copy_relay<<<dim3((B_ * H_) / 256), 256, 0, stream>>>(relay, out + (size_t)B_ * L_ * H_);
}